// Round 6
// baseline (560.462 us; speedup 1.0000x reference)
//
#include <hip/hip_runtime.h>

#define D_IN    784
#define HDIM    512
#define BATCH_N 1024
#define TC      4

#define WT_FLOATS   ((size_t)D_IN * HDIM)        // 401408
#define CKPT_STRIDE ((size_t)BATCH_N * HDIM)     // 524288 floats per slot

__device__ __forceinline__ float relu_(float v) { return fmaxf(v, 0.0f); }
__device__ __forceinline__ float sigmoid_(float v) {
    return __builtin_amdgcn_rcpf(1.0f + __expf(-v));
}

// ---------------------------------------------------------------------------
// LDS-tiled transpose in_W [H][D] -> wT [D][H] (both sides coalesced)
// ---------------------------------------------------------------------------
__global__ __launch_bounds__(256, 2)
void transpose_inW(const float* __restrict__ inW, float* __restrict__ wT) {
    __shared__ float tile[32][33];
    const int ti = blockIdx.x * 32;
    const int th = blockIdx.y * 32;
    const int lx = threadIdx.x & 31;
    const int ly = threadIdx.x >> 5;
    #pragma unroll
    for (int rr = 0; rr < 4; ++rr) {
        int h = th + ly + rr * 8;
        int i = ti + lx;
        float v = (i < D_IN) ? inW[(size_t)h * D_IN + i] : 0.0f;
        tile[ly + rr * 8][lx] = v;
    }
    __syncthreads();
    #pragma unroll
    for (int rr = 0; rr < 4; ++rr) {
        int i = ti + ly + rr * 8;
        if (i < D_IN) wT[(size_t)i * HDIM + th + lx] = tile[lx][ly + rr * 8];
    }
}

// ---------------------------------------------------------------------------
// Pass 1: G[k][b][h] = sum_{i in seg k} x[b,i]*wT[i][h]  -> ckpt slot k+1
// ---------------------------------------------------------------------------
__global__ __launch_bounds__(256, 4)
void seg_sums(const float* __restrict__ x, const float* __restrict__ wT,
              float* __restrict__ ckpt, int seglen) {
    const int rt = blockIdx.x;
    const int k  = blockIdx.y;
    const int tid = threadIdx.x;
    const int r2 = tid >> 5;
    const int hc = tid & 31;
    const int r0 = rt * 16 + r2;
    const int r1 = r0 + 8;
    const int i0 = k * seglen;

    float acc0[16], acc1[16];
    #pragma unroll
    for (int j = 0; j < 16; ++j) { acc0[j] = 0.0f; acc1[j] = 0.0f; }

    const float* x0 = x + (size_t)r0 * D_IN + i0;
    const float* x1 = x + (size_t)r1 * D_IN + i0;
    const float* w  = wT + (size_t)i0 * HDIM + hc * 4;

    float4 xa = *(const float4*)x0;
    float4 xb = *(const float4*)x1;
    for (int i = 0; i < seglen; i += 4) {
        float4 xa_n = xa, xb_n = xb;
        if (i + 4 < seglen) {
            xa_n = *(const float4*)(x0 + i + 4);
            xb_n = *(const float4*)(x1 + i + 4);
        }
        const float xav[4] = {xa.x, xa.y, xa.z, xa.w};
        const float xbv[4] = {xb.x, xb.y, xb.z, xb.w};
        #pragma unroll
        for (int s = 0; s < 4; ++s) {
            const float* wr = w + (size_t)(i + s) * HDIM;
            #pragma unroll
            for (int j = 0; j < 4; ++j) {
                float4 wv = *(const float4*)(wr + j * 128);
                acc0[4*j+0] = fmaf(xav[s], wv.x, acc0[4*j+0]);
                acc0[4*j+1] = fmaf(xav[s], wv.y, acc0[4*j+1]);
                acc0[4*j+2] = fmaf(xav[s], wv.z, acc0[4*j+2]);
                acc0[4*j+3] = fmaf(xav[s], wv.w, acc0[4*j+3]);
                acc1[4*j+0] = fmaf(xbv[s], wv.x, acc1[4*j+0]);
                acc1[4*j+1] = fmaf(xbv[s], wv.y, acc1[4*j+1]);
                acc1[4*j+2] = fmaf(xbv[s], wv.z, acc1[4*j+2]);
                acc1[4*j+3] = fmaf(xbv[s], wv.w, acc1[4*j+3]);
            }
        }
        xa = xa_n; xb = xb_n;
    }

    float* g0 = ckpt + (size_t)(k + 1) * CKPT_STRIDE + (size_t)r0 * HDIM + hc * 4;
    float* g1 = ckpt + (size_t)(k + 1) * CKPT_STRIDE + (size_t)r1 * HDIM + hc * 4;
    #pragma unroll
    for (int j = 0; j < 4; ++j) {
        *(float4*)(g0 + j * 128) = make_float4(acc0[4*j+0], acc0[4*j+1], acc0[4*j+2], acc0[4*j+3]);
        *(float4*)(g1 + j * 128) = make_float4(acc1[4*j+0], acc1[4*j+1], acc1[4*j+2], acc1[4*j+3]);
    }
}

// ---------------------------------------------------------------------------
// Pass 1.5: ckpt[0]=in_b ; ckpt[k] = ckpt[k-1] + G[k-1]
// ---------------------------------------------------------------------------
__global__ __launch_bounds__(256, 4)
void prefix_ck(const float* __restrict__ in_b, float* __restrict__ ckpt, int nseg) {
    int idx = blockIdx.x * 256 + threadIdx.x;
    int b  = idx >> 7;
    int hq = idx & 127;
    float* p = ckpt + (size_t)b * HDIM + hq * 4;
    float4 cur = *(const float4*)(in_b + hq * 4);
    *(float4*)p = cur;
    for (int k = 1; k < nseg; ++k) {
        float4 g = *(const float4*)(p + (size_t)k * CKPT_STRIDE);
        cur.x += g.x; cur.y += g.y; cur.z += g.z; cur.w += g.w;
        *(float4*)(p + (size_t)k * CKPT_STRIDE) = cur;
    }
}

// ---------------------------------------------------------------------------
// Pass 2: segment scan. Block = 8 waves; each wave owns 4 rows.
// Lane l owns h = {4l..4l+3} U {256+4l..256+4l+3} for all 4 rows.
// Reduction: 16 independent full 64-lane shfl_xor butterflies (verified
// idiom on this problem: R1-R3), then static cndmask select per 16-lane
// group; group g stores batch-row g.
// ---------------------------------------------------------------------------
__global__ __launch_bounds__(512, 4)
void nade_fwd4(const float* __restrict__ x,
               const float* __restrict__ ckpt,
               const float* __restrict__ hW,
               const float* __restrict__ h_b,
               const float* __restrict__ wT,
               float* __restrict__ out,
               int seglen, int nch) {
    __shared__ float sbuf[2][2 * TC * HDIM];    // 32 KB

    const int tid = threadIdx.x;
    const int w   = tid >> 6;
    const int l   = tid & 63;
    const int k   = blockIdx.y;
    const int base = k * seglen;
    const int row0 = blockIdx.x * 32 + w * 4;
    const int g    = l >> 4;

    float a[4][8];
    #pragma unroll
    for (int r = 0; r < 4; ++r) {
        const float* ap = ckpt + (size_t)k * CKPT_STRIDE + (size_t)(row0 + r) * HDIM;
        float4 a0 = *(const float4*)(ap + 4 * l);
        float4 a1 = *(const float4*)(ap + 256 + 4 * l);
        a[r][0]=a0.x; a[r][1]=a0.y; a[r][2]=a0.z; a[r][3]=a0.w;
        a[r][4]=a1.x; a[r][5]=a1.y; a[r][6]=a1.z; a[r][7]=a1.w;
    }

    const float* hbp = h_b + base;
    float* optr = out + (size_t)(row0 + g) * D_IN + base;

#define STAGE4(buf_, c_) {                                                                 \
        const size_t i0_ = (size_t)(base + (c_) * TC) * HDIM;                              \
        const float* src_ = (w < 4) ? (hW + i0_ + (size_t)w * 512)                         \
                                    : (wT + i0_ + (size_t)(w - 4) * 512);                  \
        float* dst_ = &sbuf[buf_][(w & 3) * 512 + (w >> 2) * 2048];                        \
        __builtin_amdgcn_global_load_lds(                                                  \
            (const __attribute__((address_space(1))) void*)(src_ + l * 4),                 \
            (__attribute__((address_space(3))) void*)(dst_ + l * 4), 16, 0, 0);            \
        __builtin_amdgcn_global_load_lds(                                                  \
            (const __attribute__((address_space(1))) void*)(src_ + 256 + l * 4),           \
            (__attribute__((address_space(3))) void*)(dst_ + 256 + l * 4), 16, 0, 0);      \
    }

    STAGE4(0, 0);
    float4 xc[4], xn[4];
    #pragma unroll
    for (int r = 0; r < 4; ++r)
        xc[r] = *(const float4*)(x + (size_t)(row0 + r) * D_IN + base);
    float4 hbc = *(const float4*)(hbp);
    float4 hbn = hbc;
    __syncthreads();    // drains vmcnt(0): buf0 staged

    for (int c = 0; c < nch; ++c) {
        const int buf = c & 1;
        if (c + 1 < nch) {
            STAGE4(buf ^ 1, c + 1);
            #pragma unroll
            for (int r = 0; r < 4; ++r)
                xn[r] = *(const float4*)(x + (size_t)(row0 + r) * D_IN + base + (c + 1) * 4);
            hbn = *(const float4*)(hbp + (c + 1) * 4);
        }

        float part[4][4];
        #pragma unroll
        for (int t = 0; t < TC; ++t) {
            const float* hp = &sbuf[buf][t * HDIM];
            float4 h0 = *(const float4*)(hp + 4 * l);
            float4 h1 = *(const float4*)(hp + 256 + 4 * l);
            #pragma unroll
            for (int r = 0; r < 4; ++r) {
                float p0 = relu_(a[r][0]) * h0.x;
                p0 = fmaf(relu_(a[r][1]), h0.y, p0);
                p0 = fmaf(relu_(a[r][2]), h0.z, p0);
                p0 = fmaf(relu_(a[r][3]), h0.w, p0);
                float p1 = relu_(a[r][4]) * h1.x;
                p1 = fmaf(relu_(a[r][5]), h1.y, p1);
                p1 = fmaf(relu_(a[r][6]), h1.z, p1);
                p1 = fmaf(relu_(a[r][7]), h1.w, p1);
                part[r][t] = p0 + p1;
            }

            // rank-1 update; x in {0.0, 1.0} exactly, wave-uniform per row
            const float xt0 = (t == 0) ? xc[0].x : (t == 1) ? xc[0].y : (t == 2) ? xc[0].z : xc[0].w;
            const float xt1 = (t == 0) ? xc[1].x : (t == 1) ? xc[1].y : (t == 2) ? xc[1].z : xc[1].w;
            const float xt2 = (t == 0) ? xc[2].x : (t == 1) ? xc[2].y : (t == 2) ? xc[2].z : xc[2].w;
            const float xt3 = (t == 0) ? xc[3].x : (t == 1) ? xc[3].y : (t == 2) ? xc[3].z : xc[3].w;
            if (xt0 + xt1 + xt2 + xt3 != 0.0f) {
                const float* wp = &sbuf[buf][2048 + t * HDIM];
                float4 w0 = *(const float4*)(wp + 4 * l);
                float4 w1 = *(const float4*)(wp + 256 + 4 * l);
                if (xt0 != 0.0f) {
                    a[0][0]+=w0.x; a[0][1]+=w0.y; a[0][2]+=w0.z; a[0][3]+=w0.w;
                    a[0][4]+=w1.x; a[0][5]+=w1.y; a[0][6]+=w1.z; a[0][7]+=w1.w;
                }
                if (xt1 != 0.0f) {
                    a[1][0]+=w0.x; a[1][1]+=w0.y; a[1][2]+=w0.z; a[1][3]+=w0.w;
                    a[1][4]+=w1.x; a[1][5]+=w1.y; a[1][6]+=w1.z; a[1][7]+=w1.w;
                }
                if (xt2 != 0.0f) {
                    a[2][0]+=w0.x; a[2][1]+=w0.y; a[2][2]+=w0.z; a[2][3]+=w0.w;
                    a[2][4]+=w1.x; a[2][5]+=w1.y; a[2][6]+=w1.z; a[2][7]+=w1.w;
                }
                if (xt3 != 0.0f) {
                    a[3][0]+=w0.x; a[3][1]+=w0.y; a[3][2]+=w0.z; a[3][3]+=w0.w;
                    a[3][4]+=w1.x; a[3][5]+=w1.y; a[3][6]+=w1.z; a[3][7]+=w1.w;
                }
            }
        }

        // 16 independent full-wave butterflies (pipelined; verified idiom)
        #pragma unroll
        for (int s = 1; s < 64; s <<= 1) {
            #pragma unroll
            for (int r = 0; r < 4; ++r) {
                #pragma unroll
                for (int t = 0; t < TC; ++t)
                    part[r][t] += __shfl_xor(part[r][t], s, 64);
            }
        }

        // group g stores batch-row g (static selects only)
        #pragma unroll
        for (int t = 0; t < TC; ++t) {
            float myv = (g == 0) ? part[0][t]
                      : (g == 1) ? part[1][t]
                      : (g == 2) ? part[2][t]
                                 : part[3][t];
            const float hbt = (t == 0) ? hbc.x : (t == 1) ? hbc.y : (t == 2) ? hbc.z : hbc.w;
            float sv = sigmoid_(myv + hbt);
            if ((l & 15) == 0) optr[c * 4 + t] = sv;
        }

        #pragma unroll
        for (int r = 0; r < 4; ++r) xc[r] = xn[r];
        hbc = hbn;
        __syncthreads();
    }
#undef STAGE4
}

// ---------------------------------------------------------------------------
// Fallback (tiny ws)
// ---------------------------------------------------------------------------
__global__ __launch_bounds__(64, 1)
void nade_fwd_fallback(const float* __restrict__ x,
                       const float* __restrict__ in_W,
                       const float* __restrict__ in_b,
                       const float* __restrict__ hW,
                       const float* __restrict__ h_b,
                       float* __restrict__ out) {
    const int b  = blockIdx.x;
    const int l  = threadIdx.x;
    const int h0 = l * 8;

    float a[8];
    {
        float4 b0 = *(const float4*)(in_b + h0);
        float4 b1 = *(const float4*)(in_b + h0 + 4);
        a[0]=b0.x; a[1]=b0.y; a[2]=b0.z; a[3]=b0.w;
        a[4]=b1.x; a[5]=b1.y; a[6]=b1.z; a[7]=b1.w;
    }
    const float* xrow = x + (size_t)b * D_IN;
    float* orow = out + (size_t)b * D_IN;

    for (int i = 0; i < D_IN; ++i) {
        const float4 hw0 = *(const float4*)(hW + (size_t)i * HDIM + h0);
        const float4 hw1 = *(const float4*)(hW + (size_t)i * HDIM + h0 + 4);
        float p;
        p = relu_(a[0]) * hw0.x;
        p = fmaf(relu_(a[1]), hw0.y, p);
        p = fmaf(relu_(a[2]), hw0.z, p);
        p = fmaf(relu_(a[3]), hw0.w, p);
        p = fmaf(relu_(a[4]), hw1.x, p);
        p = fmaf(relu_(a[5]), hw1.y, p);
        p = fmaf(relu_(a[6]), hw1.z, p);
        p = fmaf(relu_(a[7]), hw1.w, p);
        #pragma unroll
        for (int s = 1; s < 64; s <<= 1) p += __shfl_xor(p, s, 64);
        if (l == 0) orow[i] = sigmoid_(p + h_b[i]);

        const float xi = xrow[i];
        if (xi != 0.0f) {
            a[0] = fmaf(xi, in_W[(size_t)(h0+0)*D_IN + i], a[0]);
            a[1] = fmaf(xi, in_W[(size_t)(h0+1)*D_IN + i], a[1]);
            a[2] = fmaf(xi, in_W[(size_t)(h0+2)*D_IN + i], a[2]);
            a[3] = fmaf(xi, in_W[(size_t)(h0+3)*D_IN + i], a[3]);
            a[4] = fmaf(xi, in_W[(size_t)(h0+4)*D_IN + i], a[4]);
            a[5] = fmaf(xi, in_W[(size_t)(h0+5)*D_IN + i], a[5]);
            a[6] = fmaf(xi, in_W[(size_t)(h0+6)*D_IN + i], a[6]);
            a[7] = fmaf(xi, in_W[(size_t)(h0+7)*D_IN + i], a[7]);
        }
    }
}

extern "C" void kernel_launch(void* const* d_in, const int* in_sizes, int n_in,
                              void* d_out, int out_size, void* d_ws, size_t ws_size,
                              hipStream_t stream) {
    const float* x    = (const float*)d_in[0];
    const float* in_W = (const float*)d_in[1];
    const float* in_b = (const float*)d_in[2];
    const float* hW   = (const float*)d_in[3];
    const float* h_b  = (const float*)d_in[4];
    float* out = (float*)d_out;

    int nseg = 0;
    const size_t need14 = (WT_FLOATS + 14 * CKPT_STRIDE) * sizeof(float);
    const size_t need7  = (WT_FLOATS +  7 * CKPT_STRIDE) * sizeof(float);
    if      (ws_size >= need14) nseg = 14;
    else if (ws_size >= need7)  nseg = 7;

    if (nseg) {
        const int seglen = D_IN / nseg;
        float* wT   = (float*)d_ws;
        float* ckpt = wT + WT_FLOATS;

        hipLaunchKernelGGL(transpose_inW,
                           dim3((D_IN + 31) / 32, HDIM / 32), dim3(256), 0, stream,
                           in_W, wT);
        hipLaunchKernelGGL(seg_sums,
                           dim3(BATCH_N / 16, nseg - 1), dim3(256), 0, stream,
                           x, wT, ckpt, seglen);
        hipLaunchKernelGGL(prefix_ck,
                           dim3(BATCH_N * (HDIM / 4) / 256), dim3(256), 0, stream,
                           in_b, ckpt, nseg);
        hipLaunchKernelGGL(nade_fwd4,
                           dim3(BATCH_N / 32, nseg), dim3(512), 0, stream,
                           x, ckpt, hW, h_b, wT, out, seglen, seglen / TC);
    } else {
        hipLaunchKernelGGL(nade_fwd_fallback,
                           dim3(BATCH_N), dim3(64), 0, stream,
                           x, in_W, in_b, hW, h_b, out);
    }
}

// Round 7
// 152.598 us; speedup vs baseline: 3.6728x; 3.6728x over previous
//
#include <hip/hip_runtime.h>

#define D_IN    784
#define HDIM    512
#define BATCH_N 1024
#define TC      4

#define WT_FLOATS   ((size_t)D_IN * HDIM)        // 401408
#define CKPT_STRIDE ((size_t)BATCH_N * HDIM)     // 524288 floats per slot

__device__ __forceinline__ float relu_(float v) { return fmaxf(v, 0.0f); }
__device__ __forceinline__ float sigmoid_(float v) {
    return __builtin_amdgcn_rcpf(1.0f + __expf(-v));
}

// ---------------------------------------------------------------------------
// LDS-tiled transpose in_W [H][D] -> wT [D][H] (both sides coalesced)
// ---------------------------------------------------------------------------
__global__ __launch_bounds__(256, 2)
void transpose_inW(const float* __restrict__ inW, float* __restrict__ wT) {
    __shared__ float tile[32][33];
    const int ti = blockIdx.x * 32;
    const int th = blockIdx.y * 32;
    const int lx = threadIdx.x & 31;
    const int ly = threadIdx.x >> 5;
    #pragma unroll
    for (int rr = 0; rr < 4; ++rr) {
        int h = th + ly + rr * 8;
        int i = ti + lx;
        float v = (i < D_IN) ? inW[(size_t)h * D_IN + i] : 0.0f;
        tile[ly + rr * 8][lx] = v;
    }
    __syncthreads();
    #pragma unroll
    for (int rr = 0; rr < 4; ++rr) {
        int i = ti + ly + rr * 8;
        if (i < D_IN) wT[(size_t)i * HDIM + th + lx] = tile[lx][ly + rr * 8];
    }
}

// ---------------------------------------------------------------------------
// Pass 1: G[k][b][h] = sum_{i in seg k} x[b,i]*wT[i][h]  -> ckpt slot k+1
// ---------------------------------------------------------------------------
__global__ __launch_bounds__(256, 4)
void seg_sums(const float* __restrict__ x, const float* __restrict__ wT,
              float* __restrict__ ckpt, int seglen) {
    const int rt = blockIdx.x;
    const int k  = blockIdx.y;
    const int tid = threadIdx.x;
    const int r2 = tid >> 5;
    const int hc = tid & 31;
    const int r0 = rt * 16 + r2;
    const int r1 = r0 + 8;
    const int i0 = k * seglen;

    float acc0[16], acc1[16];
    #pragma unroll
    for (int j = 0; j < 16; ++j) { acc0[j] = 0.0f; acc1[j] = 0.0f; }

    const float* x0 = x + (size_t)r0 * D_IN + i0;
    const float* x1 = x + (size_t)r1 * D_IN + i0;
    const float* w  = wT + (size_t)i0 * HDIM + hc * 4;

    float4 xa = *(const float4*)x0;
    float4 xb = *(const float4*)x1;
    for (int i = 0; i < seglen; i += 4) {
        float4 xa_n = xa, xb_n = xb;
        if (i + 4 < seglen) {
            xa_n = *(const float4*)(x0 + i + 4);
            xb_n = *(const float4*)(x1 + i + 4);
        }
        const float xav[4] = {xa.x, xa.y, xa.z, xa.w};
        const float xbv[4] = {xb.x, xb.y, xb.z, xb.w};
        #pragma unroll
        for (int s = 0; s < 4; ++s) {
            const float* wr = w + (size_t)(i + s) * HDIM;
            #pragma unroll
            for (int j = 0; j < 4; ++j) {
                float4 wv = *(const float4*)(wr + j * 128);
                acc0[4*j+0] = fmaf(xav[s], wv.x, acc0[4*j+0]);
                acc0[4*j+1] = fmaf(xav[s], wv.y, acc0[4*j+1]);
                acc0[4*j+2] = fmaf(xav[s], wv.z, acc0[4*j+2]);
                acc0[4*j+3] = fmaf(xav[s], wv.w, acc0[4*j+3]);
                acc1[4*j+0] = fmaf(xbv[s], wv.x, acc1[4*j+0]);
                acc1[4*j+1] = fmaf(xbv[s], wv.y, acc1[4*j+1]);
                acc1[4*j+2] = fmaf(xbv[s], wv.z, acc1[4*j+2]);
                acc1[4*j+3] = fmaf(xbv[s], wv.w, acc1[4*j+3]);
            }
        }
        xa = xa_n; xb = xb_n;
    }

    float* g0 = ckpt + (size_t)(k + 1) * CKPT_STRIDE + (size_t)r0 * HDIM + hc * 4;
    float* g1 = ckpt + (size_t)(k + 1) * CKPT_STRIDE + (size_t)r1 * HDIM + hc * 4;
    #pragma unroll
    for (int j = 0; j < 4; ++j) {
        *(float4*)(g0 + j * 128) = make_float4(acc0[4*j+0], acc0[4*j+1], acc0[4*j+2], acc0[4*j+3]);
        *(float4*)(g1 + j * 128) = make_float4(acc1[4*j+0], acc1[4*j+1], acc1[4*j+2], acc1[4*j+3]);
    }
}

// ---------------------------------------------------------------------------
// Pass 1.5: ckpt[0]=in_b ; ckpt[k] = ckpt[k-1] + G[k-1]
// ---------------------------------------------------------------------------
__global__ __launch_bounds__(256, 4)
void prefix_ck(const float* __restrict__ in_b, float* __restrict__ ckpt, int nseg) {
    int idx = blockIdx.x * 256 + threadIdx.x;
    int b  = idx >> 7;
    int hq = idx & 127;
    float* p = ckpt + (size_t)b * HDIM + hq * 4;
    float4 cur = *(const float4*)(in_b + hq * 4);
    *(float4*)p = cur;
    for (int k = 1; k < nseg; ++k) {
        float4 g = *(const float4*)(p + (size_t)k * CKPT_STRIDE);
        cur.x += g.x; cur.y += g.y; cur.z += g.z; cur.w += g.w;
        *(float4*)(p + (size_t)k * CKPT_STRIDE) = cur;
    }
}

// ---------------------------------------------------------------------------
// Pass 2: segment scan. Block = 8 waves; wave owns 4 batch rows.
// Lane l owns h = {4l..4l+3} U {256+4l..256+4l+3} for all 4 rows.
// x handled as per-segment ballot bitmasks (wave-uniform, SGPR).
// Reduction: per-wave LDS transpose scratch (R2-verified idiom), 2 passes
// of 8 outputs; 26 DS ops/chunk vs 96-shuffle butterfly.
// ---------------------------------------------------------------------------
__global__ __launch_bounds__(512, 2)
void nade_fwd5(const float* __restrict__ x,
               const float* __restrict__ ckpt,
               const float* __restrict__ hW,
               const float* __restrict__ h_b,
               const float* __restrict__ wT,
               float* __restrict__ out,
               int seglen, int nch) {
    __shared__ float sbuf[2][2 * TC * HDIM];   // 32 KB weights double-buffer
    __shared__ float sred[8][8 * 68];          // per-wave reduction scratch (17 KB)

    const int tid = threadIdx.x;
    const int w   = tid >> 6;
    const int l   = tid & 63;
    const int k   = blockIdx.y;
    const int base = k * seglen;
    const int row0 = blockIdx.x * 32 + w * 4;

    // accumulators from checkpoint k
    float a[4][8];
    #pragma unroll
    for (int r = 0; r < 4; ++r) {
        const float* ap = ckpt + (size_t)k * CKPT_STRIDE + (size_t)(row0 + r) * HDIM;
        float4 a0 = *(const float4*)(ap + 4 * l);
        float4 a1 = *(const float4*)(ap + 256 + 4 * l);
        a[r][0]=a0.x; a[r][1]=a0.y; a[r][2]=a0.z; a[r][3]=a0.w;
        a[r][4]=a1.x; a[r][5]=a1.y; a[r][6]=a1.z; a[r][7]=a1.w;
    }

    // x bitmasks (x is exactly 0.0/1.0); wave-uniform -> SGPRs
    unsigned long long lo0, lo1, lo2, lo3;
    unsigned long long hi0 = 0, hi1 = 0, hi2 = 0, hi3 = 0;
    {
        const float* xr0 = x + (size_t)(row0 + 0) * D_IN + base;
        const float* xr1 = x + (size_t)(row0 + 1) * D_IN + base;
        const float* xr2 = x + (size_t)(row0 + 2) * D_IN + base;
        const float* xr3 = x + (size_t)(row0 + 3) * D_IN + base;
        float v;
        v = (l < seglen) ? xr0[l] : 0.0f; lo0 = __ballot(v != 0.0f);
        v = (l < seglen) ? xr1[l] : 0.0f; lo1 = __ballot(v != 0.0f);
        v = (l < seglen) ? xr2[l] : 0.0f; lo2 = __ballot(v != 0.0f);
        v = (l < seglen) ? xr3[l] : 0.0f; lo3 = __ballot(v != 0.0f);
        if (seglen > 64) {
            v = (64 + l < seglen) ? xr0[64 + l] : 0.0f; hi0 = __ballot(v != 0.0f);
            v = (64 + l < seglen) ? xr1[64 + l] : 0.0f; hi1 = __ballot(v != 0.0f);
            v = (64 + l < seglen) ? xr2[64 + l] : 0.0f; hi2 = __ballot(v != 0.0f);
            v = (64 + l < seglen) ? xr3[64 + l] : 0.0f; hi3 = __ballot(v != 0.0f);
        }
    }

    // reduction-team geometry: output o8 = l>>3 (rr=o8>>2 of pass, t=o8&3)
    const int o8   = l >> 3;
    const int j8   = l & 7;
    const int tsel = o8 & 3;
    const int rsel = o8 >> 2;       // row offset within pass (0/1)
    float* optrA = out + (size_t)(row0 + rsel) * D_IN + base + tsel;       // pass 0
    float* optrB = optrA + 2 * D_IN;                                       // pass 1

#define STAGE5(buf_, c_) {                                                                 \
        const size_t i0_ = (size_t)(base + (c_) * TC) * HDIM;                              \
        const float* src_ = (w < 4) ? (hW + i0_ + (size_t)w * 512)                         \
                                    : (wT + i0_ + (size_t)(w - 4) * 512);                  \
        float* dst_ = &sbuf[buf_][(w & 3) * 512 + (w >> 2) * 2048];                        \
        __builtin_amdgcn_global_load_lds(                                                  \
            (const __attribute__((address_space(1))) void*)(src_ + l * 4),                 \
            (__attribute__((address_space(3))) void*)(dst_ + l * 4), 16, 0, 0);            \
        __builtin_amdgcn_global_load_lds(                                                  \
            (const __attribute__((address_space(1))) void*)(src_ + 256 + l * 4),           \
            (__attribute__((address_space(3))) void*)(dst_ + 256 + l * 4), 16, 0, 0);      \
    }

    STAGE5(0, 0);
    __syncthreads();    // barrier drains vmcnt(0): buf0 staged

    for (int c = 0; c < nch; ++c) {
        const int buf = c & 1;
        if (c + 1 < nch) STAGE5(buf ^ 1, c + 1);

        const int sh = c * TC;
        const int s2 = sh & 63;
        const unsigned b0 = (unsigned)((((sh >= 64) ? hi0 : lo0) >> s2) & 15ull);
        const unsigned b1 = (unsigned)((((sh >= 64) ? hi1 : lo1) >> s2) & 15ull);
        const unsigned b2 = (unsigned)((((sh >= 64) ? hi2 : lo2) >> s2) & 15ull);
        const unsigned b3 = (unsigned)((((sh >= 64) ? hi3 : lo3) >> s2) & 15ull);
        const unsigned bu = b0 | b1 | b2 | b3;

        float4 hbc = *(const float4*)(h_b + base + sh);

        float part[4][4];
        #pragma unroll
        for (int t = 0; t < TC; ++t) {
            const float* hp = &sbuf[buf][t * HDIM];
            float4 h0 = *(const float4*)(hp + 4 * l);
            float4 h1 = *(const float4*)(hp + 256 + 4 * l);
            #pragma unroll
            for (int r = 0; r < 4; ++r) {
                float p0 = relu_(a[r][0]) * h0.x;
                p0 = fmaf(relu_(a[r][1]), h0.y, p0);
                p0 = fmaf(relu_(a[r][2]), h0.z, p0);
                p0 = fmaf(relu_(a[r][3]), h0.w, p0);
                float p1 = relu_(a[r][4]) * h1.x;
                p1 = fmaf(relu_(a[r][5]), h1.y, p1);
                p1 = fmaf(relu_(a[r][6]), h1.z, p1);
                p1 = fmaf(relu_(a[r][7]), h1.w, p1);
                part[r][t] = p0 + p1;
            }

            const unsigned bt = 1u << t;
            if (bu & bt) {           // wave-uniform branch
                const float* wp = &sbuf[buf][2048 + t * HDIM];
                float4 w0 = *(const float4*)(wp + 4 * l);
                float4 w1 = *(const float4*)(wp + 256 + 4 * l);
                if (b0 & bt) {
                    a[0][0]+=w0.x; a[0][1]+=w0.y; a[0][2]+=w0.z; a[0][3]+=w0.w;
                    a[0][4]+=w1.x; a[0][5]+=w1.y; a[0][6]+=w1.z; a[0][7]+=w1.w;
                }
                if (b1 & bt) {
                    a[1][0]+=w0.x; a[1][1]+=w0.y; a[1][2]+=w0.z; a[1][3]+=w0.w;
                    a[1][4]+=w1.x; a[1][5]+=w1.y; a[1][6]+=w1.z; a[1][7]+=w1.w;
                }
                if (b2 & bt) {
                    a[2][0]+=w0.x; a[2][1]+=w0.y; a[2][2]+=w0.z; a[2][3]+=w0.w;
                    a[2][4]+=w1.x; a[2][5]+=w1.y; a[2][6]+=w1.z; a[2][7]+=w1.w;
                }
                if (b3 & bt) {
                    a[3][0]+=w0.x; a[3][1]+=w0.y; a[3][2]+=w0.z; a[3][3]+=w0.w;
                    a[3][4]+=w1.x; a[3][5]+=w1.y; a[3][6]+=w1.z; a[3][7]+=w1.w;
                }
            }
        }

        // reduction: two passes of 8 outputs via per-wave LDS transpose.
        // pass p covers rows {2p, 2p+1}: output o8 -> (row 2p+(o8>>2), t=o8&3)
        #pragma unroll
        for (int p = 0; p < 2; ++p) {
            #pragma unroll
            for (int rr = 0; rr < 2; ++rr) {
                #pragma unroll
                for (int t = 0; t < TC; ++t)
                    sred[w][(rr * 4 + t) * 68 + l] = part[2 * p + rr][t];
            }
            const float* pr = &sred[w][o8 * 68 + j8 * 8];
            float4 q0 = *(const float4*)(pr);
            float4 q1 = *(const float4*)(pr + 4);
            float v = ((q0.x + q0.y) + (q0.z + q0.w)) + ((q1.x + q1.y) + (q1.z + q1.w));
            v += __shfl_xor(v, 1, 64);
            v += __shfl_xor(v, 2, 64);
            v += __shfl_xor(v, 4, 64);
            const float hbt = (tsel & 2) ? ((tsel & 1) ? hbc.w : hbc.z)
                                         : ((tsel & 1) ? hbc.y : hbc.x);
            float sv = sigmoid_(v + hbt);
            if (j8 == 0) {
                if (p == 0) optrA[sh] = sv;
                else        optrB[sh] = sv;
            }
        }
        __syncthreads();
    }
#undef STAGE5
}

// ---------------------------------------------------------------------------
// Fallback (tiny ws)
// ---------------------------------------------------------------------------
__global__ __launch_bounds__(64, 1)
void nade_fwd_fallback(const float* __restrict__ x,
                       const float* __restrict__ in_W,
                       const float* __restrict__ in_b,
                       const float* __restrict__ hW,
                       const float* __restrict__ h_b,
                       float* __restrict__ out) {
    const int b  = blockIdx.x;
    const int l  = threadIdx.x;
    const int h0 = l * 8;

    float a[8];
    {
        float4 b0 = *(const float4*)(in_b + h0);
        float4 b1 = *(const float4*)(in_b + h0 + 4);
        a[0]=b0.x; a[1]=b0.y; a[2]=b0.z; a[3]=b0.w;
        a[4]=b1.x; a[5]=b1.y; a[6]=b1.z; a[7]=b1.w;
    }
    const float* xrow = x + (size_t)b * D_IN;
    float* orow = out + (size_t)b * D_IN;

    for (int i = 0; i < D_IN; ++i) {
        const float4 hw0 = *(const float4*)(hW + (size_t)i * HDIM + h0);
        const float4 hw1 = *(const float4*)(hW + (size_t)i * HDIM + h0 + 4);
        float p;
        p = relu_(a[0]) * hw0.x;
        p = fmaf(relu_(a[1]), hw0.y, p);
        p = fmaf(relu_(a[2]), hw0.z, p);
        p = fmaf(relu_(a[3]), hw0.w, p);
        p = fmaf(relu_(a[4]), hw1.x, p);
        p = fmaf(relu_(a[5]), hw1.y, p);
        p = fmaf(relu_(a[6]), hw1.z, p);
        p = fmaf(relu_(a[7]), hw1.w, p);
        #pragma unroll
        for (int s = 1; s < 64; s <<= 1) p += __shfl_xor(p, s, 64);
        if (l == 0) orow[i] = sigmoid_(p + h_b[i]);

        const float xi = xrow[i];
        if (xi != 0.0f) {
            a[0] = fmaf(xi, in_W[(size_t)(h0+0)*D_IN + i], a[0]);
            a[1] = fmaf(xi, in_W[(size_t)(h0+1)*D_IN + i], a[1]);
            a[2] = fmaf(xi, in_W[(size_t)(h0+2)*D_IN + i], a[2]);
            a[3] = fmaf(xi, in_W[(size_t)(h0+3)*D_IN + i], a[3]);
            a[4] = fmaf(xi, in_W[(size_t)(h0+4)*D_IN + i], a[4]);
            a[5] = fmaf(xi, in_W[(size_t)(h0+5)*D_IN + i], a[5]);
            a[6] = fmaf(xi, in_W[(size_t)(h0+6)*D_IN + i], a[6]);
            a[7] = fmaf(xi, in_W[(size_t)(h0+7)*D_IN + i], a[7]);
        }
    }
}

extern "C" void kernel_launch(void* const* d_in, const int* in_sizes, int n_in,
                              void* d_out, int out_size, void* d_ws, size_t ws_size,
                              hipStream_t stream) {
    const float* x    = (const float*)d_in[0];
    const float* in_W = (const float*)d_in[1];
    const float* in_b = (const float*)d_in[2];
    const float* hW   = (const float*)d_in[3];
    const float* h_b  = (const float*)d_in[4];
    float* out = (float*)d_out;

    int nseg = 0;
    const size_t need14 = (WT_FLOATS + 14 * CKPT_STRIDE) * sizeof(float);
    const size_t need7  = (WT_FLOATS +  7 * CKPT_STRIDE) * sizeof(float);
    if      (ws_size >= need14) nseg = 14;
    else if (ws_size >= need7)  nseg = 7;

    if (nseg) {
        const int seglen = D_IN / nseg;
        float* wT   = (float*)d_ws;
        float* ckpt = wT + WT_FLOATS;

        hipLaunchKernelGGL(transpose_inW,
                           dim3((D_IN + 31) / 32, HDIM / 32), dim3(256), 0, stream,
                           in_W, wT);
        hipLaunchKernelGGL(seg_sums,
                           dim3(BATCH_N / 16, nseg - 1), dim3(256), 0, stream,
                           x, wT, ckpt, seglen);
        hipLaunchKernelGGL(prefix_ck,
                           dim3(BATCH_N * (HDIM / 4) / 256), dim3(256), 0, stream,
                           in_b, ckpt, nseg);
        hipLaunchKernelGGL(nade_fwd5,
                           dim3(BATCH_N / 32, nseg), dim3(512), 0, stream,
                           x, ckpt, hW, h_b, wT, out, seglen, seglen / TC);
    } else {
        hipLaunchKernelGGL(nade_fwd_fallback,
                           dim3(BATCH_N), dim3(64), 0, stream,
                           x, in_W, in_b, hW, h_b, out);
    }
}